// Round 7
// baseline (225.604 us; speedup 1.0000x reference)
//
#include <hip/hip_runtime.h>

#define B_ 4
#define S_ 2048
#define H_ 2048
#define R_ 64
#define DKV_ 1024

typedef __attribute__((ext_vector_type(8))) short s16x8;
typedef __attribute__((ext_vector_type(4))) short s16x4;
typedef __attribute__((ext_vector_type(4))) float f32x4v;

__device__ __forceinline__ unsigned short f2bf(float x) {
  unsigned int u = __builtin_bit_cast(unsigned int, x);
  u += 0x7FFF + ((u >> 16) & 1);
  return (unsigned short)(u >> 16);
}
__device__ __forceinline__ float bf2f(unsigned short h) {
  unsigned int u = ((unsigned int)h) << 16;
  return __builtin_bit_cast(float, u);
}

__device__ __forceinline__ void gl_lds16(const void* g, void* l) {
  __builtin_amdgcn_global_load_lds(
      (const __attribute__((address_space(1))) unsigned int*)g,
      (__attribute__((address_space(3))) unsigned int*)l, 16, 0, 0);
}

// swizzled byte offset within a [rows][32 bf16] LDS tile (2-way max bank alias)
__device__ __forceinline__ int swz_off(int m, int kb) {
  int L = m >> 1;
  int slot = ((m & 1) << 2) | (kb >> 4);
  int sp = slot ^ (L & 7);
  return (L << 7) | (sp << 4) | (kb & 15);
}

// ---------------- fp32 -> bf16 hi + lo split ----------------
__global__ __launch_bounds__(256) void k_f32_to_bf16x2(const float* __restrict__ in,
    unsigned short* __restrict__ hi, unsigned short* __restrict__ lo, int n4) {
  int i = blockIdx.x * 256 + threadIdx.x;
  if (i >= n4) return;
  float4 v = ((const float4*)in)[i];
  ushort4 h, l;
  h.x = f2bf(v.x); h.y = f2bf(v.y); h.z = f2bf(v.z); h.w = f2bf(v.w);
  l.x = f2bf(v.x - bf2f(h.x)); l.y = f2bf(v.y - bf2f(h.y));
  l.z = f2bf(v.z - bf2f(h.z)); l.w = f2bf(v.w - bf2f(h.w));
  ((ushort4*)hi)[i] = h;
  ((ushort4*)lo)[i] = l;
}

// ---------------- transpose fp32 [rows][cols] -> bf16 [cols][rows] ----------------
__global__ __launch_bounds__(256) void k_transpose_bf16(const float* __restrict__ in,
    unsigned short* __restrict__ out, int rows, int cols) {
  __shared__ float tile[32][33];
  int c0 = blockIdx.x * 32, r0 = blockIdx.y * 32;
  int tx = threadIdx.x & 31, ty = threadIdx.x >> 5;
  for (int i = 0; i < 4; ++i)
    tile[ty + i * 8][tx] = in[(size_t)(r0 + ty + i * 8) * cols + c0 + tx];
  __syncthreads();
  for (int i = 0; i < 4; ++i)
    out[(size_t)(c0 + ty + i * 8) * rows + r0 + tx] = f2bf(tile[tx][ty + i * 8]);
}

// ---------------- WqkT hi/lo: [128 n][2048 k] from Wq,Wk [2048][64] ----------------
__global__ __launch_bounds__(256) void k_build_wqkt(const float* __restrict__ Wq,
    const float* __restrict__ Wk, unsigned short* __restrict__ hiT,
    unsigned short* __restrict__ loT) {
  __shared__ float tile[32][33];
  int k0 = blockIdx.x * 32, n0 = blockIdx.y * 32;
  const float* W = (n0 < 64) ? Wq : Wk;
  int nb = n0 & 63;
  int tx = threadIdx.x & 31, ty = threadIdx.x >> 5;
  for (int i = 0; i < 4; ++i)
    tile[ty + i * 8][tx] = W[(size_t)(k0 + ty + i * 8) * R_ + nb + tx];
  __syncthreads();
  for (int i = 0; i < 4; ++i) {
    float v = tile[tx][ty + i * 8];
    unsigned short h = f2bf(v);
    size_t idx = (size_t)(n0 + ty + i * 8) * H_ + k0 + tx;
    hiT[idx] = h;
    loT[idx] = f2bf(v - bf2f(h));
  }
}

// ---------------- WoT_eff[n][r] = Wo[h1(r)][n] + Wo[h1(r)+128][n], bf16 ----------------
__global__ __launch_bounds__(256) void k_build_wot(const float* __restrict__ Wo,
                                                   unsigned short* __restrict__ WoT) {
  __shared__ float tile[32][33];
  int n0 = blockIdx.x * 32, r0 = blockIdx.y * 32;
  int h1b = 256 * (r0 >> 7) + (r0 & 127);
  int tx = threadIdx.x & 31, ty = threadIdx.x >> 5;
  for (int i = 0; i < 4; ++i) {
    int dr = ty + i * 8;
    tile[dr][tx] = Wo[(size_t)(h1b + dr) * H_ + n0 + tx] +
                   Wo[(size_t)(h1b + 128 + dr) * H_ + n0 + tx];
  }
  __syncthreads();
  for (int i = 0; i < 4; ++i)
    WoT[(size_t)(n0 + ty + i * 8) * DKV_ + r0 + tx] = f2bf(tile[tx][ty + i * 8]);
}

// ---------------- q/k projection via split-bf16 MFMA; 3-buffer counted-vmcnt pipeline ----------------
__global__ __launch_bounds__(256) void k_qk_mfma(
    const unsigned short* __restrict__ Ahi, const unsigned short* __restrict__ Alo,
    const unsigned short* __restrict__ Bhi, const unsigned short* __restrict__ Blo,
    unsigned short* __restrict__ qkh, unsigned short* __restrict__ qkl) {
  // per-buffer layout: AsH[0,2K) AsL[2K,4K) BsH[4K,12K) BsL[12K,20K)
  constexpr int TQK = 20480;
  __shared__ __attribute__((aligned(16))) char lds[3 * TQK];
  int m0 = blockIdx.x * 32;
  int t = threadIdx.x;
  int lane = t & 63, wave = t >> 6;
  int lr = lane & 15, kb = (lane >> 4) << 4;

  auto stage = [&](int kt, int buf) {
    int k0 = kt << 5;
    char* base = &lds[buf * TQK];
    {  // A hi (waves 0,1) / lo (waves 2,3): 128 chunks each
      int q = t & 127;
      int L = q >> 3;
      int slot = (q & 7) ^ (L & 7);
      int m = (L << 1) | (slot >> 2);
      int ke = (slot & 3) << 3;
      const unsigned short* src =
          (t < 128 ? Ahi : Alo) + (size_t)(m0 + m) * H_ + k0 + ke;
      gl_lds16(src, base + (t < 128 ? 0 : 2048) + q * 16);
    }
#pragma unroll
    for (int c = 0; c < 2; ++c) {  // B hi: 512 chunks
      int q = c * 256 + t;
      int L = q >> 3;
      int slot = (q & 7) ^ (L & 7);
      int n = (L << 1) | (slot >> 2);
      int ke = (slot & 3) << 3;
      gl_lds16(Bhi + (size_t)n * H_ + k0 + ke, base + 4096 + q * 16);
    }
#pragma unroll
    for (int c = 0; c < 2; ++c) {  // B lo: 512 chunks
      int q = c * 256 + t;
      int L = q >> 3;
      int slot = (q & 7) ^ (L & 7);
      int n = (L << 1) | (slot >> 2);
      int ke = (slot & 3) << 3;
      gl_lds16(Blo + (size_t)n * H_ + k0 + ke, base + 12288 + q * 16);
    }
  };

  f32x4v acc[2][2] = {};
  stage(0, 0);
  stage(1, 1);
  int cur = 0, nxt = 2;
  for (int kt = 0; kt < 64; ++kt) {
    __builtin_amdgcn_sched_barrier(0);
    if (kt < 63) asm volatile("s_waitcnt vmcnt(5)" ::: "memory");
    else asm volatile("s_waitcnt vmcnt(0)" ::: "memory");
    __builtin_amdgcn_s_barrier();
    __builtin_amdgcn_sched_barrier(0);
    if (kt + 2 < 64) stage(kt + 2, nxt);
    const char* base = &lds[cur * TQK];
    s16x8 ah[2], al[2], bh[2], bl[2];
#pragma unroll
    for (int m = 0; m < 2; ++m) {
      int o = swz_off(m * 16 + lr, kb);
      ah[m] = *(const s16x8*)(base + o);
      al[m] = *(const s16x8*)(base + 2048 + o);
    }
#pragma unroll
    for (int n = 0; n < 2; ++n) {
      int o = swz_off(wave * 32 + n * 16 + lr, kb);
      bh[n] = *(const s16x8*)(base + 4096 + o);
      bl[n] = *(const s16x8*)(base + 12288 + o);
    }
    __builtin_amdgcn_s_setprio(1);
#pragma unroll
    for (int m = 0; m < 2; ++m)
#pragma unroll
      for (int n = 0; n < 2; ++n) {
        acc[m][n] = __builtin_amdgcn_mfma_f32_16x16x32_bf16(ah[m], bh[n], acc[m][n], 0, 0, 0);
        acc[m][n] = __builtin_amdgcn_mfma_f32_16x16x32_bf16(ah[m], bl[n], acc[m][n], 0, 0, 0);
        acc[m][n] = __builtin_amdgcn_mfma_f32_16x16x32_bf16(al[m], bh[n], acc[m][n], 0, 0, 0);
      }
    __builtin_amdgcn_s_setprio(0);
    cur = (cur == 2) ? 0 : cur + 1;
    nxt = (nxt == 2) ? 0 : nxt + 1;
  }
  for (int m = 0; m < 2; ++m) {
    int lrow = m * 16 + ((lane >> 4) << 2);
    for (int n = 0; n < 2; ++n) {
      int lcol = wave * 32 + n * 16 + lr;
      for (int r = 0; r < 4; ++r) {
        float v = acc[m][n][r];
        unsigned short h = f2bf(v);
        size_t idx = (size_t)(m0 + lrow + r) * 128 + lcol;
        qkh[idx] = h;
        qkl[idx] = f2bf(v - bf2f(h));
      }
    }
  }
}

// ---------------- fused scores+exp+rowsum+PV, in-register P ----------------
// Per block: 64 q-rows x 256 d, batch z. Wave roles: iq=wave&3 owns 16 i-rows,
// wd=wave>>2 owns 128 d (QK^T duplicated across wd; PV split by wd).
// QK^T is computed SWAPPED (mfma(A=Kfrag, B=Qfrag) -> S^T): each lane then
// holds P[i=lane&15][j=(lane>>4)*4+r], which is exactly the A-operand layout
// of v_mfma_f32_16x16x16_bf16 -> P feeds PV directly from registers.
// No P LDS, no rowsum LDS/atomics, ONE barrier per 32-j step (DMA buffers only).
__global__ __launch_bounds__(512, 4) void k_attn_fused(
    const unsigned short* __restrict__ qkh, const unsigned short* __restrict__ qkl,
    const unsigned short* __restrict__ VT, unsigned short* __restrict__ ctx) {
  constexpr int TILEB = 24576;  // k: 4x2KB swizzled subtiles; V: 16KB linear [256][32]
  __shared__ __attribute__((aligned(16))) char lds[3 * TILEB];

  int t = threadIdx.x;
  int gx = gridDim.x;  // 32
  int x = blockIdx.x;
  int bx = (x & 1) ? (gx - 1 - (x >> 1)) : (x >> 1);  // heavy+light pairing
  if (blockIdx.z & 2) bx = gx - 1 - bx;               // stride-256 pairing
  int z = blockIdx.z;
  int m0 = bx * 64, d0 = blockIdx.y * 256;

  int lane = t & 63, wave = t >> 6;
  int iq = wave & 3, wd = wave >> 2;
  int kb = (lane >> 4) << 4;

  const unsigned short* qh = qkh + (size_t)z * S_ * 128;
  const unsigned short* ql = qkl + (size_t)z * S_ * 128;

  // Q as B-operand frags: row i = lane&15, rank chunk (lane>>4)*8 (+32)
  s16x8 qfh[2], qfl[2];
  {
    size_t rq = (size_t)(m0 + iq * 16 + (lane & 15)) * 128 + ((lane >> 4) << 3);
    qfh[0] = *(const s16x8*)(qh + rq);
    qfh[1] = *(const s16x8*)(qh + rq + 32);
    qfl[0] = *(const s16x8*)(ql + rq);
    qfl[1] = *(const s16x8*)(ql + rq + 32);
  }

  auto stage = [&](int kt, int buf) {
    int j0 = kt << 5;
    char* base = &lds[buf * TILEB];
    {  // k rows [32 j][32 rank] x {hi-r0, hi-r32, lo-r0, lo-r32}; swizzled
      int q = t & 127;
      int L = q >> 3;
      int slot = (q & 7) ^ (L & 7);
      int jr = (L << 1) | (slot >> 2);
      int ke = (slot & 3) << 3;
      int sub = t >> 7;
      const unsigned short* src = ((sub < 2) ? qh : ql) +
          (size_t)(j0 + jr) * 128 + 64 + ((sub & 1) << 5) + ke;
      gl_lds16(src, base + sub * 2048 + q * 16);
    }
    char* vb = base + 8192;  // V tile [256 d][32 j] linear, 64B rows
#pragma unroll
    for (int c = 0; c < 2; ++c) {
      int q = c * 512 + t;
      int dr = q >> 2, jc = (q & 3) << 3;
      gl_lds16(VT + (size_t)(d0 + dr) * (B_ * S_) + (size_t)z * S_ + j0 + jc,
               vb + q * 16);
    }
  };

  int NT = (m0 + 64) >> 5;  // causal j extent
  stage(0, 0);
  stage(1, 1);

  int ko0 = swz_off(lane & 15, kb);        // h=0 k-frag row
  int ko1 = swz_off(16 + (lane & 15), kb); // h=1 k-frag row
  float ps = 0.f;
  f32x4v accp[8] = {};
  int ig = m0 + iq * 16 + (lane & 15);

  int cur = 0, nxt = 2;
  for (int kt = 0; kt < NT; ++kt) {
    __builtin_amdgcn_sched_barrier(0);
    if (kt + 1 < NT) asm volatile("s_waitcnt vmcnt(3)" ::: "memory");
    else asm volatile("s_waitcnt vmcnt(0)" ::: "memory");
    __builtin_amdgcn_s_barrier();
    __builtin_amdgcn_sched_barrier(0);
    if (kt + 2 < NT) stage(kt + 2, nxt);
    const char* base = &lds[cur * TILEB];
    // ---- swapped QK^T per j-half h: S^T frag, exp+mask+pack in-reg ----
    s16x4 pa[2];
#pragma unroll
    for (int h = 0; h < 2; ++h) {
      int ko = h ? ko1 : ko0;
      s16x8 kh0 = *(const s16x8*)(base + ko);
      s16x8 kh1 = *(const s16x8*)(base + 2048 + ko);
      s16x8 kl0 = *(const s16x8*)(base + 4096 + ko);
      s16x8 kl1 = *(const s16x8*)(base + 6144 + ko);
      f32x4v s = {};
      s = __builtin_amdgcn_mfma_f32_16x16x32_bf16(kh0, qfh[0], s, 0, 0, 0);
      s = __builtin_amdgcn_mfma_f32_16x16x32_bf16(kh1, qfh[1], s, 0, 0, 0);
      s = __builtin_amdgcn_mfma_f32_16x16x32_bf16(kl0, qfh[0], s, 0, 0, 0);
      s = __builtin_amdgcn_mfma_f32_16x16x32_bf16(kl1, qfh[1], s, 0, 0, 0);
      s = __builtin_amdgcn_mfma_f32_16x16x32_bf16(kh0, qfl[0], s, 0, 0, 0);
      s = __builtin_amdgcn_mfma_f32_16x16x32_bf16(kh1, qfl[1], s, 0, 0, 0);
      int jb = (kt << 5) + h * 16 + ((lane >> 4) << 2);
      s16x4 p;
#pragma unroll
      for (int r = 0; r < 4; ++r) {
        float pv = (jb + r <= ig) ? __expf(s[r]) : 0.f;
        ps += pv;
        p[r] = (short)f2bf(pv);
      }
      pa[h] = p;
    }
    // ---- PV: 16i x 128d per wave via 16x16x16 MFMA (P = A-operand in-reg) ----
    const char* vb = base + 8192;
    int jby = (lane >> 4) << 3;  // j byte offset within row for this lane group
    __builtin_amdgcn_s_setprio(1);
#pragma unroll
    for (int nf = 0; nf < 8; ++nf) {
      int dl = wd * 128 + nf * 16 + (lane & 15);
#pragma unroll
      for (int h = 0; h < 2; ++h) {
        s16x4 vf = *(const s16x4*)(vb + dl * 64 + h * 32 + jby);
        asm volatile("v_mfma_f32_16x16x16_bf16 %0, %1, %2, %0"
                     : "+v"(accp[nf]) : "v"(pa[h]), "v"(vf));
      }
    }
    __builtin_amdgcn_s_setprio(0);
    cur = (cur == 2) ? 0 : cur + 1;
    nxt = (nxt == 2) ? 0 : nxt + 1;
  }

  // ---- rowsum reduce across the 4 lane-groups (all in-wave) ----
  ps += __shfl_xor(ps, 16, 64);
  ps += __shfl_xor(ps, 32, 64);
  float rcp[4];
#pragma unroll
  for (int r = 0; r < 4; ++r)
    rcp[r] = 1.f / __shfl(ps, ((lane >> 4) << 2) + r, 64);

  // ---- scale + write ctx (D: row i = (lane>>4)*4+r, col d = lane&15) ----
  unsigned short* Cp = ctx + (size_t)(z * S_ + m0 + iq * 16) * DKV_ + d0 + wd * 128;
  int r0 = (lane >> 4) << 2;
#pragma unroll
  for (int nf = 0; nf < 8; ++nf) {
    int lc = nf * 16 + (lane & 15);
#pragma unroll
    for (int r = 0; r < 4; ++r)
      Cp[(size_t)(r0 + r) * DKV_ + lc] = f2bf(accp[nf][r] * rcp[r]);
  }
}

// ---------------- pipelined bf16 MFMA GEMM (wave 64x64) ----------------
// C[m][n] = sum_k A[m][k] * BT[n][k]; 512 threads, 8 waves 4Mx2N, BK=32,
// 3-buffer LDS pipeline, counted vmcnt depth-2, swizzled LDS.
template <int BM, int BN, bool TRANS_OUT, bool OUT_BF16>
__global__ __launch_bounds__(512, 4) void k_gemm256(
    const unsigned short* __restrict__ A, int lda,
    const unsigned short* __restrict__ BT, int ldbt,
    void* __restrict__ C, int ldc, int K) {
  constexpr int ABYTES = BM * 64;
  constexpr int BBYTES = BN * 64;
  constexpr int TILEB = ABYTES + BBYTES;
  constexpr int WARPS_M = 4;
  constexpr int WARPS_N = 2;
  constexpr int WM = BM / WARPS_M;
  constexpr int WN = BN / WARPS_N;
  constexpr int MF = WM / 16;
  constexpr int NF = WN / 16;
  constexpr int LPS = BM / 128 + BN / 128;
  __shared__ __attribute__((aligned(16))) char lds[3 * TILEB];

  int t = threadIdx.x;
  int gx = gridDim.x;
  int id = blockIdx.y * gx + blockIdx.x;
  int cpx = gx >> 3;
  int xcd = id & 7, rr = id >> 3;
  int bx = xcd * cpx + rr % cpx;  // contiguous bx-chunk per XCD
  int by = rr / cpx;
  int m0 = bx * BM, n0 = by * BN;

  const unsigned short* Ab = A + (size_t)m0 * lda;
  const unsigned short* Bb = BT + (size_t)n0 * ldbt;

  int lane = t & 63, wave = t >> 6;
  int wr = wave / WARPS_N, wc = wave % WARPS_N;
  int kb = (lane >> 4) << 4;
  int aoff[MF], boff[NF];
#pragma unroll
  for (int mf = 0; mf < MF; ++mf)
    aoff[mf] = swz_off(wr * WM + mf * 16 + (lane & 15), kb);
#pragma unroll
  for (int nf = 0; nf < NF; ++nf)
    boff[nf] = swz_off(wc * WN + nf * 16 + (lane & 15), kb);

  int NT = K >> 5;

  auto stage = [&](int kt, int buf) {
    int k0 = kt << 5;
    char* la = &lds[buf * TILEB];
    char* lb = la + ABYTES;
#pragma unroll
    for (int c = 0; c < BM / 128; ++c) {
      int q = c * 512 + t;
      int L = q >> 3;
      int slot = (q & 7) ^ (L & 7);
      int m = (L << 1) | (slot >> 2);
      int ke = (slot & 3) << 3;
      gl_lds16(Ab + (size_t)m * lda + k0 + ke, la + q * 16);
    }
#pragma unroll
    for (int c = 0; c < BN / 128; ++c) {
      int q = c * 512 + t;
      int L = q >> 3;
      int slot = (q & 7) ^ (L & 7);
      int n = (L << 1) | (slot >> 2);
      int ke = (slot & 3) << 3;
      gl_lds16(Bb + (size_t)n * ldbt + k0 + ke, lb + q * 16);
    }
  };

  f32x4v acc[MF][NF] = {};
  stage(0, 0);
  if (NT > 1) stage(1, 1);
  int cur = 0, nxt = 2;
  for (int kt = 0; kt < NT; ++kt) {
    __builtin_amdgcn_sched_barrier(0);
    if (kt + 1 < NT) {
      if constexpr (LPS == 2) asm volatile("s_waitcnt vmcnt(2)" ::: "memory");
      else asm volatile("s_waitcnt vmcnt(3)" ::: "memory");
    } else {
      asm volatile("s_waitcnt vmcnt(0)" ::: "memory");
    }
    __builtin_amdgcn_s_barrier();
    __builtin_amdgcn_sched_barrier(0);
    if (kt + 2 < NT) stage(kt + 2, nxt);
    const char* la = &lds[cur * TILEB];
    const char* lb = la + ABYTES;
    s16x8 af[MF], bf[NF];
#pragma unroll
    for (int mf = 0; mf < MF; ++mf) af[mf] = *(const s16x8*)(la + aoff[mf]);
#pragma unroll
    for (int nf = 0; nf < NF; ++nf) bf[nf] = *(const s16x8*)(lb + boff[nf]);
    __builtin_amdgcn_s_setprio(1);
#pragma unroll
    for (int mf = 0; mf < MF; ++mf)
#pragma unroll
      for (int nf = 0; nf < NF; ++nf)
        acc[mf][nf] =
            __builtin_amdgcn_mfma_f32_16x16x32_bf16(af[mf], bf[nf], acc[mf][nf], 0, 0, 0);
    __builtin_amdgcn_s_setprio(0);
    cur = (cur == 2) ? 0 : cur + 1;
    nxt = (nxt == 2) ? 0 : nxt + 1;
  }

#pragma unroll
  for (int mf = 0; mf < MF; ++mf) {
    int lrow = wr * WM + mf * 16 + ((lane >> 4) << 2);
#pragma unroll
    for (int nf = 0; nf < NF; ++nf) {
      int lcol = wc * WN + nf * 16 + (lane & 15);
      f32x4v v = acc[mf][nf];
      if (TRANS_OUT) {
        ushort4 o;
        o.x = f2bf(v[0]); o.y = f2bf(v[1]); o.z = f2bf(v[2]); o.w = f2bf(v[3]);
        unsigned short* Cp = (unsigned short*)C;
        *(ushort4*)&Cp[(size_t)(n0 + lcol) * ldc + m0 + lrow] = o;
      } else {
#pragma unroll
        for (int r = 0; r < 4; ++r) {
          if (OUT_BF16) {
            unsigned short* Cp = (unsigned short*)C;
            Cp[(size_t)(m0 + lrow + r) * ldc + n0 + lcol] = f2bf(v[r]);
          } else {
            float* Cp = (float*)C;
            Cp[(size_t)(m0 + lrow + r) * ldc + n0 + lcol] = v[r];
          }
        }
      }
    }
  }
}

extern "C" void kernel_launch(void* const* d_in, const int* in_sizes, int n_in,
                              void* d_out, int out_size, void* d_ws, size_t ws_size,
                              hipStream_t stream) {
  const float* hs = (const float*)d_in[0];
  const float* Wq = (const float*)d_in[2];
  const float* Wk = (const float*)d_in[3];
  const float* Wv = (const float*)d_in[4];
  const float* Wo = (const float*)d_in[5];
  float* out = (float*)d_out;

  char* w = (char*)d_ws;
  unsigned short* hsb = (unsigned short*)w; w += (size_t)B_ * S_ * H_ * 2;
  unsigned short* hsl = (unsigned short*)w; w += (size_t)B_ * S_ * H_ * 2;
  unsigned short* WvT = (unsigned short*)w; w += (size_t)DKV_ * H_ * 2;
  unsigned short* WoT = (unsigned short*)w; w += (size_t)H_ * DKV_ * 2;
  unsigned short* WqkTh = (unsigned short*)w; w += (size_t)128 * H_ * 2;
  unsigned short* WqkTl = (unsigned short*)w; w += (size_t)128 * H_ * 2;
  unsigned short* VT  = (unsigned short*)w; w += (size_t)DKV_ * B_ * S_ * 2;
  unsigned short* ctx = (unsigned short*)w; w += (size_t)B_ * S_ * DKV_ * 2;
  unsigned short* qkh = (unsigned short*)w; w += (size_t)B_ * S_ * 128 * 2;
  unsigned short* qkl = (unsigned short*)w; w += (size_t)B_ * S_ * 128 * 2;

  // 1) hs -> bf16 hi + lo
  k_f32_to_bf16x2<<<(B_ * S_ * H_ / 4 + 255) / 256, 256, 0, stream>>>(
      hs, hsb, hsl, B_ * S_ * H_ / 4);
  // 2) WvT = Wv^T bf16
  k_transpose_bf16<<<dim3(DKV_ / 32, H_ / 32), 256, 0, stream>>>(Wv, WvT, H_, DKV_);
  // 3) WoT_eff
  k_build_wot<<<dim3(H_ / 32, DKV_ / 32), 256, 0, stream>>>(Wo, WoT);
  // 4) WqkT hi/lo
  k_build_wqkt<<<dim3(H_ / 32, 4), 256, 0, stream>>>(Wq, Wk, WqkTh, WqkTl);
  // 5) q/k projection -> bf16 hi/lo q,k (pipelined)
  k_qk_mfma<<<B_ * S_ / 32, 256, 0, stream>>>(hsb, hsl, WqkTh, WqkTl, qkh, qkl);
  // 6) V projection (transposed epilogue -> VT): BM=256xBN=128, wave 64x64
  k_gemm256<256, 128, true, true>
      <<<dim3(B_ * S_ / 256, DKV_ / 128), 512, 0, stream>>>(
      hsb, H_, WvT, H_, VT, B_ * S_, H_);
  // 7) fused scores+exp+rowsum+PV -> ctx (512 blocks, 2/CU, paired causal)
  k_attn_fused<<<dim3(32, 4, B_), 512, 0, stream>>>(qkh, qkl, VT, ctx);
  // 8) out = ctx @ WoT^T (fp32 out): BM=256xBN=128, wave 64x64
  k_gemm256<256, 128, false, false>
      <<<dim3(B_ * S_ / 256, H_ / 128), 512, 0, stream>>>(
      ctx, DKV_, WoT, DKV_, out, H_, DKV_);
}

// Round 8
// 199.532 us; speedup vs baseline: 1.1307x; 1.1307x over previous
//
#include <hip/hip_runtime.h>

#define B_ 4
#define S_ 2048
#define H_ 2048
#define R_ 64
#define DKV_ 1024

typedef __attribute__((ext_vector_type(8))) short s16x8;
typedef __attribute__((ext_vector_type(4))) float f32x4v;

__device__ __forceinline__ unsigned short f2bf(float x) {
  unsigned int u = __builtin_bit_cast(unsigned int, x);
  u += 0x7FFF + ((u >> 16) & 1);
  return (unsigned short)(u >> 16);
}
__device__ __forceinline__ float bf2f(unsigned short h) {
  unsigned int u = ((unsigned int)h) << 16;
  return __builtin_bit_cast(float, u);
}

__device__ __forceinline__ void gl_lds16(const void* g, void* l) {
  __builtin_amdgcn_global_load_lds(
      (const __attribute__((address_space(1))) unsigned int*)g,
      (__attribute__((address_space(3))) unsigned int*)l, 16, 0, 0);
}

// swizzled byte offset within a [rows][32 bf16] LDS tile (2-way max bank alias)
__device__ __forceinline__ int swz_off(int m, int kb) {
  int L = m >> 1;
  int slot = ((m & 1) << 2) | (kb >> 4);
  int sp = slot ^ (L & 7);
  return (L << 7) | (sp << 4) | (kb & 15);
}

// ---------------- transpose fp32 [rows][cols] -> bf16 [cols][rows] ----------------
__global__ __launch_bounds__(256) void k_transpose_bf16(const float* __restrict__ in,
    unsigned short* __restrict__ out, int rows, int cols) {
  __shared__ float tile[32][33];
  int c0 = blockIdx.x * 32, r0 = blockIdx.y * 32;
  int tx = threadIdx.x & 31, ty = threadIdx.x >> 5;
  for (int i = 0; i < 4; ++i)
    tile[ty + i * 8][tx] = in[(size_t)(r0 + ty + i * 8) * cols + c0 + tx];
  __syncthreads();
  for (int i = 0; i < 4; ++i)
    out[(size_t)(c0 + ty + i * 8) * rows + r0 + tx] = f2bf(tile[tx][ty + i * 8]);
}

// ---------------- WqkT hi/lo: [128 n][2048 k] from Wq,Wk [2048][64] ----------------
__global__ __launch_bounds__(256) void k_build_wqkt(const float* __restrict__ Wq,
    const float* __restrict__ Wk, unsigned short* __restrict__ hiT,
    unsigned short* __restrict__ loT) {
  __shared__ float tile[32][33];
  int k0 = blockIdx.x * 32, n0 = blockIdx.y * 32;
  const float* W = (n0 < 64) ? Wq : Wk;
  int nb = n0 & 63;
  int tx = threadIdx.x & 31, ty = threadIdx.x >> 5;
  for (int i = 0; i < 4; ++i)
    tile[ty + i * 8][tx] = W[(size_t)(k0 + ty + i * 8) * R_ + nb + tx];
  __syncthreads();
  for (int i = 0; i < 4; ++i) {
    float v = tile[tx][ty + i * 8];
    unsigned short h = f2bf(v);
    size_t idx = (size_t)(n0 + ty + i * 8) * H_ + k0 + tx;
    hiT[idx] = h;
    loT[idx] = f2bf(v - bf2f(h));
  }
}

// ---------------- WoT_eff[n][r] = Wo[h1(r)][n] + Wo[h1(r)+128][n], bf16 ----------------
__global__ __launch_bounds__(256) void k_build_wot(const float* __restrict__ Wo,
                                                   unsigned short* __restrict__ WoT) {
  __shared__ float tile[32][33];
  int n0 = blockIdx.x * 32, r0 = blockIdx.y * 32;
  int h1b = 256 * (r0 >> 7) + (r0 & 127);
  int tx = threadIdx.x & 31, ty = threadIdx.x >> 5;
  for (int i = 0; i < 4; ++i) {
    int dr = ty + i * 8;
    tile[dr][tx] = Wo[(size_t)(h1b + dr) * H_ + n0 + tx] +
                   Wo[(size_t)(h1b + 128 + dr) * H_ + n0 + tx];
  }
  __syncthreads();
  for (int i = 0; i < 4; ++i)
    WoT[(size_t)(n0 + ty + i * 8) * DKV_ + r0 + tx] = f2bf(tile[tx][ty + i * 8]);
}

// ---------------- fused fp32-split + q/k projection ----------------
// Reads hs fp32 directly; converts each 32x32 A-tile to bf16 hi/lo in registers,
// ds_writes into the swizzled LDS layout, and stores the hi part to hsb (for
// V-proj) -- eliminating the separate split kernel and the hsl tensor.
// B (WqkT hi/lo) stays on the DMA path. Per step: 1 fp32 load + 4 DMA + 1
// store = 6 VMEM -> counted vmcnt(6) at top exactly drains B of 2 steps ago.
__global__ __launch_bounds__(256) void k_qk_fused(
    const float* __restrict__ hs,
    const unsigned short* __restrict__ Bhi, const unsigned short* __restrict__ Blo,
    unsigned short* __restrict__ hsb,
    unsigned short* __restrict__ qkh, unsigned short* __restrict__ qkl) {
  // per-buffer layout: AsH[0,2K) AsL[2K,4K) BsH[4K,12K) BsL[12K,20K)
  constexpr int TQK = 20480;
  __shared__ __attribute__((aligned(16))) char lds[3 * TQK];
  int m0 = blockIdx.x * 32;
  int t = threadIdx.x;
  int lane = t & 63, wave = t >> 6;
  int lr = lane & 15, kb = (lane >> 4) << 4;

  // A-conversion assignment: thread t -> row t>>3, fp32 cols (t&7)*4..+3
  int arow = t >> 3;
  int acol = (t & 7) << 2;
  const float* asrc = hs + (size_t)(m0 + arow) * H_ + acol;
  unsigned short* hdst = hsb + (size_t)(m0 + arow) * H_ + acol;
  int adst = swz_off(arow, ((t & 7) >> 1) << 4) + ((t & 1) << 3);

  auto stageB = [&](int kt, char* base) {
    int k0 = kt << 5;
#pragma unroll
    for (int c = 0; c < 2; ++c) {  // B hi: 512 chunks
      int q = c * 256 + t;
      int L = q >> 3;
      int slot = (q & 7) ^ (L & 7);
      int n = (L << 1) | (slot >> 2);
      int ke = (slot & 3) << 3;
      gl_lds16(Bhi + (size_t)n * H_ + k0 + ke, base + 4096 + q * 16);
    }
#pragma unroll
    for (int c = 0; c < 2; ++c) {  // B lo: 512 chunks
      int q = c * 256 + t;
      int L = q >> 3;
      int slot = (q & 7) ^ (L & 7);
      int n = (L << 1) | (slot >> 2);
      int ke = (slot & 3) << 3;
      gl_lds16(Blo + (size_t)n * H_ + k0 + ke, base + 12288 + q * 16);
    }
  };

  auto convA = [&](const float4& v, char* wbuf, int kt) {
    ushort4 h, l;
    h.x = f2bf(v.x); h.y = f2bf(v.y); h.z = f2bf(v.z); h.w = f2bf(v.w);
    l.x = f2bf(v.x - bf2f(h.x)); l.y = f2bf(v.y - bf2f(h.y));
    l.z = f2bf(v.z - bf2f(h.z)); l.w = f2bf(v.w - bf2f(h.w));
    *(ushort4*)(wbuf + adst) = h;
    *(ushort4*)(wbuf + 2048 + adst) = l;
    *(ushort4*)(hdst + (size_t)kt * 32) = h;
  };

  // prologue: A(0),B(0),A(1),B(1); convert A(0) into buf0
  float4 Rcur, Rnext;
  Rcur = *(const float4*)(asrc);
  stageB(0, &lds[0]);
  Rnext = *(const float4*)(asrc + 32);
  stageB(1, &lds[TQK]);
  convA(Rcur, &lds[0], 0);
  Rcur = Rnext;

  f32x4v acc[2][2] = {};
  int cur = 0, wb = 1, sb = 2;
  for (int kt = 0; kt < 64; ++kt) {
    __builtin_amdgcn_sched_barrier(0);
    if (kt < 62) asm volatile("s_waitcnt vmcnt(6) lgkmcnt(0)" ::: "memory");
    else asm volatile("s_waitcnt vmcnt(0) lgkmcnt(0)" ::: "memory");
    __builtin_amdgcn_s_barrier();
    __builtin_amdgcn_sched_barrier(0);
    if (kt + 2 < 64) {
      Rnext = *(const float4*)(asrc + (size_t)(kt + 2) * 32);
      stageB(kt + 2, &lds[sb * TQK]);
    }
    const char* base = &lds[cur * TQK];
    s16x8 ah[2], al[2], bh[2], bl[2];
#pragma unroll
    for (int m = 0; m < 2; ++m) {
      int o = swz_off(m * 16 + lr, kb);
      ah[m] = *(const s16x8*)(base + o);
      al[m] = *(const s16x8*)(base + 2048 + o);
    }
#pragma unroll
    for (int n = 0; n < 2; ++n) {
      int o = swz_off(wave * 32 + n * 16 + lr, kb);
      bh[n] = *(const s16x8*)(base + 4096 + o);
      bl[n] = *(const s16x8*)(base + 12288 + o);
    }
    if (kt + 1 < 64) convA(Rcur, &lds[wb * TQK], kt + 1);
    __builtin_amdgcn_s_setprio(1);
#pragma unroll
    for (int m = 0; m < 2; ++m)
#pragma unroll
      for (int n = 0; n < 2; ++n) {
        acc[m][n] = __builtin_amdgcn_mfma_f32_16x16x32_bf16(ah[m], bh[n], acc[m][n], 0, 0, 0);
        acc[m][n] = __builtin_amdgcn_mfma_f32_16x16x32_bf16(ah[m], bl[n], acc[m][n], 0, 0, 0);
        acc[m][n] = __builtin_amdgcn_mfma_f32_16x16x32_bf16(al[m], bh[n], acc[m][n], 0, 0, 0);
      }
    __builtin_amdgcn_s_setprio(0);
    Rcur = Rnext;
    cur = (cur == 2) ? 0 : cur + 1;
    wb = (wb == 2) ? 0 : wb + 1;
    sb = (sb == 2) ? 0 : sb + 1;
  }
  for (int m = 0; m < 2; ++m) {
    int lrow = m * 16 + ((lane >> 4) << 2);
    for (int n = 0; n < 2; ++n) {
      int lcol = wave * 32 + n * 16 + lr;
      for (int r = 0; r < 4; ++r) {
        float v = acc[m][n][r];
        unsigned short h = f2bf(v);
        size_t idx = (size_t)(m0 + lrow + r) * 128 + lcol;
        qkh[idx] = h;
        qkl[idx] = f2bf(v - bf2f(h));
      }
    }
  }
}

// ---------------- fused scores+exp+rowsum+PV (round-6 verified version) ----------------
__global__ __launch_bounds__(512, 4) void k_attn_fused(
    const unsigned short* __restrict__ qkh, const unsigned short* __restrict__ qkl,
    const unsigned short* __restrict__ VT, unsigned short* __restrict__ ctx) {
  constexpr int TILEB = 24576;  // k: 4x2KB subtiles, V: 16KB
  __shared__ __attribute__((aligned(16))) char lds[3 * TILEB + 4096 + 256];
  char* Pt = &lds[3 * TILEB];
  float* rs = (float*)&lds[3 * TILEB + 4096];

  int t = threadIdx.x;
  int gx = gridDim.x;  // 32
  int x = blockIdx.x;
  int bx = (x & 1) ? (gx - 1 - (x >> 1)) : (x >> 1);  // heavy+light pairing
  if (blockIdx.z & 2) bx = gx - 1 - bx;               // stride-256 pairing
  int z = blockIdx.z;
  int m0 = bx * 64, d0 = blockIdx.y * 256;

  int lane = t & 63, wave = t >> 6;
  int sm = wave >> 1, sn = wave & 1;  // QK^T role: S-frag (16i x 16j)
  int wr = wave >> 2, wc = wave & 3;  // PV role: 32i x 64d
  int kb = (lane >> 4) << 4;

  const unsigned short* qh = qkh + (size_t)z * S_ * 128;
  const unsigned short* ql = qkl + (size_t)z * S_ * 128;

  s16x8 qfh[2], qfl[2];
  {
    size_t rq = (size_t)(m0 + sm * 16 + (lane & 15)) * 128 + ((lane >> 4) << 3);
    qfh[0] = *(const s16x8*)(qh + rq);
    qfh[1] = *(const s16x8*)(qh + rq + 32);
    qfl[0] = *(const s16x8*)(ql + rq);
    qfl[1] = *(const s16x8*)(ql + rq + 32);
  }

  auto stage = [&](int kt, int buf) {
    int j0 = kt << 5;
    char* base = &lds[buf * TILEB];
    {
      int q = t & 127;
      int L = q >> 3;
      int slot = (q & 7) ^ (L & 7);
      int jr = (L << 1) | (slot >> 2);
      int ke = (slot & 3) << 3;
      int sub = t >> 7;
      const unsigned short* src = ((sub < 2) ? qh : ql) +
          (size_t)(j0 + jr) * 128 + 64 + ((sub & 1) << 5) + ke;
      gl_lds16(src, base + sub * 2048 + q * 16);
    }
    char* vb = base + 8192;  // V tile [256 d][32 j]
#pragma unroll
    for (int c = 0; c < 2; ++c) {
      int q = c * 512 + t;
      int L = q >> 3;
      int slot = (q & 7) ^ (L & 7);
      int dr = (L << 1) | (slot >> 2);
      int ke = (slot & 3) << 3;
      gl_lds16(VT + (size_t)(d0 + dr) * (B_ * S_) + (size_t)z * S_ + j0 + ke,
               vb + q * 16);
    }
  };

  if (t < 64) rs[t] = 0.f;
  int NT = (m0 + 64) >> 5;
  stage(0, 0);
  stage(1, 1);

  int jrow = sn * 16 + (lane & 15);
  int koffs = swz_off(jrow, kb);
  int paoff[2], voff[4];
#pragma unroll
  for (int mf = 0; mf < 2; ++mf)
    paoff[mf] = swz_off(wr * 32 + mf * 16 + (lane & 15), kb);
#pragma unroll
  for (int nf = 0; nf < 4; ++nf)
    voff[nf] = swz_off(wc * 64 + nf * 16 + (lane & 15), kb);

  float ps[4] = {0.f, 0.f, 0.f, 0.f};
  f32x4v accp[2][4] = {};
  int prow = sm * 16 + ((lane >> 4) << 2);
  int pcol = sn * 16 + (lane & 15);

  int cur = 0, nxt = 2;
  for (int kt = 0; kt < NT; ++kt) {
    __builtin_amdgcn_sched_barrier(0);
    if (kt + 1 < NT) asm volatile("s_waitcnt vmcnt(3) lgkmcnt(0)" ::: "memory");
    else asm volatile("s_waitcnt vmcnt(0) lgkmcnt(0)" ::: "memory");
    __builtin_amdgcn_s_barrier();
    __builtin_amdgcn_sched_barrier(0);
    if (kt + 2 < NT) stage(kt + 2, nxt);
    const char* base = &lds[cur * TILEB];
    s16x8 kh[2], kl[2];
    kh[0] = *(const s16x8*)(base + koffs);
    kh[1] = *(const s16x8*)(base + 2048 + koffs);
    kl[0] = *(const s16x8*)(base + 4096 + koffs);
    kl[1] = *(const s16x8*)(base + 6144 + koffs);
    f32x4v s = {};
#pragma unroll
    for (int ks = 0; ks < 2; ++ks) {
      s = __builtin_amdgcn_mfma_f32_16x16x32_bf16(qfh[ks], kh[ks], s, 0, 0, 0);
      s = __builtin_amdgcn_mfma_f32_16x16x32_bf16(qfh[ks], kl[ks], s, 0, 0, 0);
      s = __builtin_amdgcn_mfma_f32_16x16x32_bf16(qfl[ks], kh[ks], s, 0, 0, 0);
    }
    int jg = (kt << 5) + pcol;
    int ig = m0 + prow;
#pragma unroll
    for (int r = 0; r < 4; ++r) {
      float p = (jg <= ig + r) ? __expf(s[r]) : 0.f;
      ps[r] += p;
      *(unsigned short*)(Pt + swz_off(prow + r, pcol * 2)) = f2bf(p);
    }
    __builtin_amdgcn_sched_barrier(0);
    asm volatile("s_waitcnt lgkmcnt(0)" ::: "memory");
    __builtin_amdgcn_s_barrier();
    __builtin_amdgcn_sched_barrier(0);
    s16x8 pa[2], vf[4];
#pragma unroll
    for (int mf = 0; mf < 2; ++mf) pa[mf] = *(const s16x8*)(Pt + paoff[mf]);
    const char* vbase = base + 8192;
#pragma unroll
    for (int nf = 0; nf < 4; ++nf) vf[nf] = *(const s16x8*)(vbase + voff[nf]);
    __builtin_amdgcn_s_setprio(1);
#pragma unroll
    for (int mf = 0; mf < 2; ++mf)
#pragma unroll
      for (int nf = 0; nf < 4; ++nf)
        accp[mf][nf] =
            __builtin_amdgcn_mfma_f32_16x16x32_bf16(pa[mf], vf[nf], accp[mf][nf], 0, 0, 0);
    __builtin_amdgcn_s_setprio(0);
    cur = (cur == 2) ? 0 : cur + 1;
    nxt = (nxt == 2) ? 0 : nxt + 1;
  }

#pragma unroll
  for (int r = 0; r < 4; ++r) {
    float v = ps[r];
    for (int msk = 1; msk < 16; msk <<= 1) v += __shfl_xor(v, msk, 64);
    if ((lane & 15) == 0) atomicAdd(&rs[prow + r], v);
  }
  __syncthreads();

  unsigned short* Cp = ctx + (size_t)(z * S_ + m0) * DKV_ + d0;
#pragma unroll
  for (int mf = 0; mf < 2; ++mf) {
    int lr0 = wr * 32 + mf * 16 + ((lane >> 4) << 2);
#pragma unroll
    for (int nf = 0; nf < 4; ++nf) {
      int lc = wc * 64 + nf * 16 + (lane & 15);
#pragma unroll
      for (int r = 0; r < 4; ++r) {
        float sc = 1.f / rs[lr0 + r];
        Cp[(size_t)(lr0 + r) * DKV_ + lc] = f2bf(accp[mf][nf][r] * sc);
      }
    }
  }
}

// ---------------- pipelined bf16 MFMA GEMM (wave 64x64) ----------------
template <int BM, int BN, bool TRANS_OUT, bool OUT_BF16>
__global__ __launch_bounds__(512, 4) void k_gemm256(
    const unsigned short* __restrict__ A, int lda,
    const unsigned short* __restrict__ BT, int ldbt,
    void* __restrict__ C, int ldc, int K) {
  constexpr int ABYTES = BM * 64;
  constexpr int BBYTES = BN * 64;
  constexpr int TILEB = ABYTES + BBYTES;
  constexpr int WARPS_M = 4;
  constexpr int WARPS_N = 2;
  constexpr int WM = BM / WARPS_M;
  constexpr int WN = BN / WARPS_N;
  constexpr int MF = WM / 16;
  constexpr int NF = WN / 16;
  constexpr int LPS = BM / 128 + BN / 128;
  __shared__ __attribute__((aligned(16))) char lds[3 * TILEB];

  int t = threadIdx.x;
  int gx = gridDim.x;
  int id = blockIdx.y * gx + blockIdx.x;
  int cpx = gx >> 3;
  int xcd = id & 7, rr = id >> 3;
  int bx = xcd * cpx + rr % cpx;
  int by = rr / cpx;
  int m0 = bx * BM, n0 = by * BN;

  const unsigned short* Ab = A + (size_t)m0 * lda;
  const unsigned short* Bb = BT + (size_t)n0 * ldbt;

  int lane = t & 63, wave = t >> 6;
  int wr = wave / WARPS_N, wc = wave % WARPS_N;
  int kb = (lane >> 4) << 4;
  int aoff[MF], boff[NF];
#pragma unroll
  for (int mf = 0; mf < MF; ++mf)
    aoff[mf] = swz_off(wr * WM + mf * 16 + (lane & 15), kb);
#pragma unroll
  for (int nf = 0; nf < NF; ++nf)
    boff[nf] = swz_off(wc * WN + nf * 16 + (lane & 15), kb);

  int NT = K >> 5;

  auto stage = [&](int kt, int buf) {
    int k0 = kt << 5;
    char* la = &lds[buf * TILEB];
    char* lb = la + ABYTES;
#pragma unroll
    for (int c = 0; c < BM / 128; ++c) {
      int q = c * 512 + t;
      int L = q >> 3;
      int slot = (q & 7) ^ (L & 7);
      int m = (L << 1) | (slot >> 2);
      int ke = (slot & 3) << 3;
      gl_lds16(Ab + (size_t)m * lda + k0 + ke, la + q * 16);
    }
#pragma unroll
    for (int c = 0; c < BN / 128; ++c) {
      int q = c * 512 + t;
      int L = q >> 3;
      int slot = (q & 7) ^ (L & 7);
      int n = (L << 1) | (slot >> 2);
      int ke = (slot & 3) << 3;
      gl_lds16(Bb + (size_t)n * ldbt + k0 + ke, lb + q * 16);
    }
  };

  f32x4v acc[MF][NF] = {};
  stage(0, 0);
  if (NT > 1) stage(1, 1);
  int cur = 0, nxt = 2;
  for (int kt = 0; kt < NT; ++kt) {
    __builtin_amdgcn_sched_barrier(0);
    if (kt + 1 < NT) {
      if constexpr (LPS == 2) asm volatile("s_waitcnt vmcnt(2)" ::: "memory");
      else asm volatile("s_waitcnt vmcnt(3)" ::: "memory");
    } else {
      asm volatile("s_waitcnt vmcnt(0)" ::: "memory");
    }
    __builtin_amdgcn_s_barrier();
    __builtin_amdgcn_sched_barrier(0);
    if (kt + 2 < NT) stage(kt + 2, nxt);
    const char* la = &lds[cur * TILEB];
    const char* lb = la + ABYTES;
    s16x8 af[MF], bf[NF];
#pragma unroll
    for (int mf = 0; mf < MF; ++mf) af[mf] = *(const s16x8*)(la + aoff[mf]);
#pragma unroll
    for (int nf = 0; nf < NF; ++nf) bf[nf] = *(const s16x8*)(lb + boff[nf]);
    __builtin_amdgcn_s_setprio(1);
#pragma unroll
    for (int mf = 0; mf < MF; ++mf)
#pragma unroll
      for (int nf = 0; nf < NF; ++nf)
        acc[mf][nf] =
            __builtin_amdgcn_mfma_f32_16x16x32_bf16(af[mf], bf[nf], acc[mf][nf], 0, 0, 0);
    __builtin_amdgcn_s_setprio(0);
    cur = (cur == 2) ? 0 : cur + 1;
    nxt = (nxt == 2) ? 0 : nxt + 1;
  }

#pragma unroll
  for (int mf = 0; mf < MF; ++mf) {
    int lrow = wr * WM + mf * 16 + ((lane >> 4) << 2);
#pragma unroll
    for (int nf = 0; nf < NF; ++nf) {
      int lcol = wc * WN + nf * 16 + (lane & 15);
      f32x4v v = acc[mf][nf];
      if (TRANS_OUT) {
        ushort4 o;
        o.x = f2bf(v[0]); o.y = f2bf(v[1]); o.z = f2bf(v[2]); o.w = f2bf(v[3]);
        unsigned short* Cp = (unsigned short*)C;
        *(ushort4*)&Cp[(size_t)(n0 + lcol) * ldc + m0 + lrow] = o;
      } else {
#pragma unroll
        for (int r = 0; r < 4; ++r) {
          if (OUT_BF16) {
            unsigned short* Cp = (unsigned short*)C;
            Cp[(size_t)(m0 + lrow + r) * ldc + n0 + lcol] = f2bf(v[r]);
          } else {
            float* Cp = (float*)C;
            Cp[(size_t)(m0 + lrow + r) * ldc + n0 + lcol] = v[r];
          }
        }
      }
    }
  }
}

extern "C" void kernel_launch(void* const* d_in, const int* in_sizes, int n_in,
                              void* d_out, int out_size, void* d_ws, size_t ws_size,
                              hipStream_t stream) {
  const float* hs = (const float*)d_in[0];
  const float* Wq = (const float*)d_in[2];
  const float* Wk = (const float*)d_in[3];
  const float* Wv = (const float*)d_in[4];
  const float* Wo = (const float*)d_in[5];
  float* out = (float*)d_out;

  char* w = (char*)d_ws;
  unsigned short* hsb = (unsigned short*)w; w += (size_t)B_ * S_ * H_ * 2;
  unsigned short* WvT = (unsigned short*)w; w += (size_t)DKV_ * H_ * 2;
  unsigned short* WoT = (unsigned short*)w; w += (size_t)H_ * DKV_ * 2;
  unsigned short* WqkTh = (unsigned short*)w; w += (size_t)128 * H_ * 2;
  unsigned short* WqkTl = (unsigned short*)w; w += (size_t)128 * H_ * 2;
  unsigned short* VT  = (unsigned short*)w; w += (size_t)DKV_ * B_ * S_ * 2;
  unsigned short* ctx = (unsigned short*)w; w += (size_t)B_ * S_ * DKV_ * 2;
  unsigned short* qkh = (unsigned short*)w; w += (size_t)B_ * S_ * 128 * 2;
  unsigned short* qkl = (unsigned short*)w; w += (size_t)B_ * S_ * 128 * 2;

  // 1) WvT = Wv^T bf16
  k_transpose_bf16<<<dim3(DKV_ / 32, H_ / 32), 256, 0, stream>>>(Wv, WvT, H_, DKV_);
  // 2) WoT_eff
  k_build_wot<<<dim3(H_ / 32, DKV_ / 32), 256, 0, stream>>>(Wo, WoT);
  // 3) WqkT hi/lo
  k_build_wqkt<<<dim3(H_ / 32, 4), 256, 0, stream>>>(Wq, Wk, WqkTh, WqkTl);
  // 4) fused split + q/k projection -> hsb, qkh, qkl
  k_qk_fused<<<B_ * S_ / 32, 256, 0, stream>>>(hs, WqkTh, WqkTl, hsb, qkh, qkl);
  // 5) V projection (transposed epilogue -> VT): BM=256xBN=128, wave 64x64
  k_gemm256<256, 128, true, true>
      <<<dim3(B_ * S_ / 256, DKV_ / 128), 512, 0, stream>>>(
      hsb, H_, WvT, H_, VT, B_ * S_, H_);
  // 6) fused scores+exp+rowsum+PV -> ctx (512 blocks, 2/CU, paired causal)
  k_attn_fused<<<dim3(32, 4, B_), 512, 0, stream>>>(qkh, qkl, VT, ctx);
  // 7) out = ctx @ WoT^T (fp32 out): BM=256xBN=128, wave 64x64
  k_gemm256<256, 128, false, false>
      <<<dim3(B_ * S_ / 256, H_ / 128), 512, 0, stream>>>(
      ctx, DKV_, WoT, DKV_, out, H_, DKV_);
}

// Round 9
// 189.149 us; speedup vs baseline: 1.1927x; 1.0549x over previous
//
#include <hip/hip_runtime.h>

#define B_ 4
#define S_ 2048
#define H_ 2048
#define R_ 64
#define DKV_ 1024

typedef __attribute__((ext_vector_type(8))) short s16x8;
typedef __attribute__((ext_vector_type(4))) float f32x4v;

__device__ __forceinline__ unsigned short f2bf(float x) {
  unsigned int u = __builtin_bit_cast(unsigned int, x);
  u += 0x7FFF + ((u >> 16) & 1);
  return (unsigned short)(u >> 16);
}
__device__ __forceinline__ float bf2f(unsigned short h) {
  unsigned int u = ((unsigned int)h) << 16;
  return __builtin_bit_cast(float, u);
}

__device__ __forceinline__ void gl_lds16(const void* g, void* l) {
  __builtin_amdgcn_global_load_lds(
      (const __attribute__((address_space(1))) unsigned int*)g,
      (__attribute__((address_space(3))) unsigned int*)l, 16, 0, 0);
}

// swizzled byte offset within a [rows][32 bf16] LDS tile (2-way max bank alias)
__device__ __forceinline__ int swz_off(int m, int kb) {
  int L = m >> 1;
  int slot = ((m & 1) << 2) | (kb >> 4);
  int sp = slot ^ (L & 7);
  return (L << 7) | (sp << 4) | (kb & 15);
}

// ---------------- transpose fp32 [rows][cols] -> bf16 [cols][rows] ----------------
__global__ __launch_bounds__(256) void k_transpose_bf16(const float* __restrict__ in,
    unsigned short* __restrict__ out, int rows, int cols) {
  __shared__ float tile[32][33];
  int c0 = blockIdx.x * 32, r0 = blockIdx.y * 32;
  int tx = threadIdx.x & 31, ty = threadIdx.x >> 5;
  for (int i = 0; i < 4; ++i)
    tile[ty + i * 8][tx] = in[(size_t)(r0 + ty + i * 8) * cols + c0 + tx];
  __syncthreads();
  for (int i = 0; i < 4; ++i)
    out[(size_t)(c0 + ty + i * 8) * rows + r0 + tx] = f2bf(tile[tx][ty + i * 8]);
}

// ---------------- WqkT hi/lo: [128 n][2048 k] from Wq,Wk [2048][64] ----------------
__global__ __launch_bounds__(256) void k_build_wqkt(const float* __restrict__ Wq,
    const float* __restrict__ Wk, unsigned short* __restrict__ hiT,
    unsigned short* __restrict__ loT) {
  __shared__ float tile[32][33];
  int k0 = blockIdx.x * 32, n0 = blockIdx.y * 32;
  const float* W = (n0 < 64) ? Wq : Wk;
  int nb = n0 & 63;
  int tx = threadIdx.x & 31, ty = threadIdx.x >> 5;
  for (int i = 0; i < 4; ++i)
    tile[ty + i * 8][tx] = W[(size_t)(k0 + ty + i * 8) * R_ + nb + tx];
  __syncthreads();
  for (int i = 0; i < 4; ++i) {
    float v = tile[tx][ty + i * 8];
    unsigned short h = f2bf(v);
    size_t idx = (size_t)(n0 + ty + i * 8) * H_ + k0 + tx;
    hiT[idx] = h;
    loT[idx] = f2bf(v - bf2f(h));
  }
}

// ---------------- WoT_eff[n][r] = Wo[h1(r)][n] + Wo[h1(r)+128][n], bf16 ----------------
__global__ __launch_bounds__(256) void k_build_wot(const float* __restrict__ Wo,
                                                   unsigned short* __restrict__ WoT) {
  __shared__ float tile[32][33];
  int n0 = blockIdx.x * 32, r0 = blockIdx.y * 32;
  int h1b = 256 * (r0 >> 7) + (r0 & 127);
  int tx = threadIdx.x & 31, ty = threadIdx.x >> 5;
  for (int i = 0; i < 4; ++i) {
    int dr = ty + i * 8;
    tile[dr][tx] = Wo[(size_t)(h1b + dr) * H_ + n0 + tx] +
                   Wo[(size_t)(h1b + 128 + dr) * H_ + n0 + tx];
  }
  __syncthreads();
  for (int i = 0; i < 4; ++i)
    WoT[(size_t)(n0 + ty + i * 8) * DKV_ + r0 + tx] = f2bf(tile[tx][ty + i * 8]);
}

// ---------------- split-K q/k projection (fused fp32->hi/lo conversion) ----------------
// Grid (256 row-tiles, 4 K-chunks) x 512 thr; LDS 40 KB -> 4 blocks/CU (full occ).
// Per block: 32 rows x 512 K, 16 steps, 2-buffer pipeline. A converted in-reg
// from fp32 (also stores hsb slice); B (WqkT hi/lo) DMA'd. Partial fp32 out.
// Per-buffer layout: AsH[0,2K) AsL[2K,4K) BsH[4K,12K) BsL[12K,20K)
__global__ __launch_bounds__(512, 8) void k_qk_split(
    const float* __restrict__ hs,
    const unsigned short* __restrict__ Bhi, const unsigned short* __restrict__ Blo,
    unsigned short* __restrict__ hsb, float* __restrict__ part) {
  constexpr int TQK = 20480;
  __shared__ __attribute__((aligned(16))) char lds[2 * TQK];
  int m0 = blockIdx.x * 32;
  int kc0 = blockIdx.y * 512;
  int t = threadIdx.x;
  int lane = t & 63, wave = t >> 6;
  int lr = lane & 15, kb = (lane >> 4) << 4;

  // A conversion: thread t -> row t>>4, 2 fp32 cols (t&15)*2
  int arow = t >> 4;
  const float* asrc = hs + (size_t)(m0 + arow) * H_ + kc0 + ((t & 15) << 1);
  unsigned short* hdst = hsb + (size_t)(m0 + arow) * H_ + kc0 + ((t & 15) << 1);
  int adst = swz_off(arow, (t & 15) << 2);

  auto stageB = [&](int kt, char* base) {
    int k0 = kc0 + (kt << 5);
    int L = t >> 3;
    int slot = (t & 7) ^ (L & 7);
    int n = (L << 1) | (slot >> 2);
    int ke = (slot & 3) << 3;
    gl_lds16(Bhi + (size_t)n * H_ + k0 + ke, base + 4096 + t * 16);
    gl_lds16(Blo + (size_t)n * H_ + k0 + ke, base + 12288 + t * 16);
  };

  auto convA = [&](const float2& v, char* wbuf, int kt) {
    ushort2 h, l;
    h.x = f2bf(v.x); h.y = f2bf(v.y);
    l.x = f2bf(v.x - bf2f(h.x)); l.y = f2bf(v.y - bf2f(h.y));
    *(ushort2*)(wbuf + adst) = h;
    *(ushort2*)(wbuf + 2048 + adst) = l;
    *(ushort2*)(hdst + (size_t)kt * 32) = h;
  };

  // prologue: R0, stageB(0), Rcur(step1); conv R0 -> buf0
  float2 R0 = *(const float2*)(asrc);
  stageB(0, &lds[0]);
  float2 Rcur = *(const float2*)(asrc + 32);
  asm volatile("s_waitcnt vmcnt(3)" ::: "memory");
  convA(R0, &lds[0], 0);

  f32x4v acc[2] = {};
  for (int kt = 0; kt < 16; ++kt) {
    char* curb = &lds[(kt & 1) * TQK];
    char* nxtb = &lds[((kt + 1) & 1) * TQK];
    if (kt + 1 < 16) stageB(kt + 1, nxtb);
    float2 Rnext;
    if (kt + 2 < 16) Rnext = *(const float2*)(asrc + (size_t)(kt + 2) * 32);
    __builtin_amdgcn_sched_barrier(0);
    if (kt + 2 < 16) asm volatile("s_waitcnt vmcnt(4) lgkmcnt(0)" ::: "memory");
    else if (kt + 1 < 16) asm volatile("s_waitcnt vmcnt(3) lgkmcnt(0)" ::: "memory");
    else asm volatile("s_waitcnt vmcnt(0) lgkmcnt(0)" ::: "memory");
    __builtin_amdgcn_s_barrier();
    __builtin_amdgcn_sched_barrier(0);
    if (kt + 1 < 16) convA(Rcur, nxtb, kt + 1);
    Rcur = Rnext;
    s16x8 ah[2], al[2], bh, bl;
#pragma unroll
    for (int m = 0; m < 2; ++m) {
      int o = swz_off(m * 16 + lr, kb);
      ah[m] = *(const s16x8*)(curb + o);
      al[m] = *(const s16x8*)(curb + 2048 + o);
    }
    {
      int o = swz_off(wave * 16 + lr, kb);
      bh = *(const s16x8*)(curb + 4096 + o);
      bl = *(const s16x8*)(curb + 12288 + o);
    }
    __builtin_amdgcn_s_setprio(1);
#pragma unroll
    for (int m = 0; m < 2; ++m) {
      acc[m] = __builtin_amdgcn_mfma_f32_16x16x32_bf16(ah[m], bh, acc[m], 0, 0, 0);
      acc[m] = __builtin_amdgcn_mfma_f32_16x16x32_bf16(ah[m], bl, acc[m], 0, 0, 0);
      acc[m] = __builtin_amdgcn_mfma_f32_16x16x32_bf16(al[m], bh, acc[m], 0, 0, 0);
    }
    __builtin_amdgcn_s_setprio(0);
  }

  float* Pp = part + (size_t)blockIdx.y * (8192 * 128);
#pragma unroll
  for (int m = 0; m < 2; ++m) {
    int lrow = m * 16 + ((lane >> 4) << 2);
    int lcol = wave * 16 + lr;
#pragma unroll
    for (int r = 0; r < 4; ++r)
      Pp[(size_t)(m0 + lrow + r) * 128 + lcol] = acc[m][r];
  }
}

// ---------------- reduce 4 split-K partials -> qkh/qkl hi/lo ----------------
__global__ __launch_bounds__(256) void k_qk_reduce(const float* __restrict__ part,
    unsigned short* __restrict__ qkh, unsigned short* __restrict__ qkl) {
  constexpr size_t CH = (size_t)8192 * 128;
  size_t i = ((size_t)blockIdx.x * 256 + threadIdx.x) * 4;
  float4 a = *(const float4*)(part + i);
  float4 b = *(const float4*)(part + CH + i);
  float4 c = *(const float4*)(part + 2 * CH + i);
  float4 d = *(const float4*)(part + 3 * CH + i);
  float v[4] = {a.x + b.x + c.x + d.x, a.y + b.y + c.y + d.y,
                a.z + b.z + c.z + d.z, a.w + b.w + c.w + d.w};
  ushort4 h, l;
  unsigned short* hp = (unsigned short*)&h;
  unsigned short* lp = (unsigned short*)&l;
#pragma unroll
  for (int r = 0; r < 4; ++r) {
    hp[r] = f2bf(v[r]);
    lp[r] = f2bf(v[r] - bf2f(hp[r]));
  }
  *(ushort4*)(qkh + i) = h;
  *(ushort4*)(qkl + i) = l;
}

// ---------------- fused scores+exp+rowsum+PV (round-6 verified version) ----------------
__global__ __launch_bounds__(512, 4) void k_attn_fused(
    const unsigned short* __restrict__ qkh, const unsigned short* __restrict__ qkl,
    const unsigned short* __restrict__ VT, unsigned short* __restrict__ ctx) {
  constexpr int TILEB = 24576;  // k: 4x2KB subtiles, V: 16KB
  __shared__ __attribute__((aligned(16))) char lds[3 * TILEB + 4096 + 256];
  char* Pt = &lds[3 * TILEB];
  float* rs = (float*)&lds[3 * TILEB + 4096];

  int t = threadIdx.x;
  int gx = gridDim.x;  // 32
  int x = blockIdx.x;
  int bx = (x & 1) ? (gx - 1 - (x >> 1)) : (x >> 1);  // heavy+light pairing
  if (blockIdx.z & 2) bx = gx - 1 - bx;               // stride-256 pairing
  int z = blockIdx.z;
  int m0 = bx * 64, d0 = blockIdx.y * 256;

  int lane = t & 63, wave = t >> 6;
  int sm = wave >> 1, sn = wave & 1;  // QK^T role: S-frag (16i x 16j)
  int wr = wave >> 2, wc = wave & 3;  // PV role: 32i x 64d
  int kb = (lane >> 4) << 4;

  const unsigned short* qh = qkh + (size_t)z * S_ * 128;
  const unsigned short* ql = qkl + (size_t)z * S_ * 128;

  s16x8 qfh[2], qfl[2];
  {
    size_t rq = (size_t)(m0 + sm * 16 + (lane & 15)) * 128 + ((lane >> 4) << 3);
    qfh[0] = *(const s16x8*)(qh + rq);
    qfh[1] = *(const s16x8*)(qh + rq + 32);
    qfl[0] = *(const s16x8*)(ql + rq);
    qfl[1] = *(const s16x8*)(ql + rq + 32);
  }

  auto stage = [&](int kt, int buf) {
    int j0 = kt << 5;
    char* base = &lds[buf * TILEB];
    {
      int q = t & 127;
      int L = q >> 3;
      int slot = (q & 7) ^ (L & 7);
      int jr = (L << 1) | (slot >> 2);
      int ke = (slot & 3) << 3;
      int sub = t >> 7;
      const unsigned short* src = ((sub < 2) ? qh : ql) +
          (size_t)(j0 + jr) * 128 + 64 + ((sub & 1) << 5) + ke;
      gl_lds16(src, base + sub * 2048 + q * 16);
    }
    char* vb = base + 8192;  // V tile [256 d][32 j]
#pragma unroll
    for (int c = 0; c < 2; ++c) {
      int q = c * 512 + t;
      int L = q >> 3;
      int slot = (q & 7) ^ (L & 7);
      int dr = (L << 1) | (slot >> 2);
      int ke = (slot & 3) << 3;
      gl_lds16(VT + (size_t)(d0 + dr) * (B_ * S_) + (size_t)z * S_ + j0 + ke,
               vb + q * 16);
    }
  };

  if (t < 64) rs[t] = 0.f;
  int NT = (m0 + 64) >> 5;
  stage(0, 0);
  stage(1, 1);

  int jrow = sn * 16 + (lane & 15);
  int koffs = swz_off(jrow, kb);
  int paoff[2], voff[4];
#pragma unroll
  for (int mf = 0; mf < 2; ++mf)
    paoff[mf] = swz_off(wr * 32 + mf * 16 + (lane & 15), kb);
#pragma unroll
  for (int nf = 0; nf < 4; ++nf)
    voff[nf] = swz_off(wc * 64 + nf * 16 + (lane & 15), kb);

  float ps[4] = {0.f, 0.f, 0.f, 0.f};
  f32x4v accp[2][4] = {};
  int prow = sm * 16 + ((lane >> 4) << 2);
  int pcol = sn * 16 + (lane & 15);

  int cur = 0, nxt = 2;
  for (int kt = 0; kt < NT; ++kt) {
    __builtin_amdgcn_sched_barrier(0);
    if (kt + 1 < NT) asm volatile("s_waitcnt vmcnt(3) lgkmcnt(0)" ::: "memory");
    else asm volatile("s_waitcnt vmcnt(0) lgkmcnt(0)" ::: "memory");
    __builtin_amdgcn_s_barrier();
    __builtin_amdgcn_sched_barrier(0);
    if (kt + 2 < NT) stage(kt + 2, nxt);
    const char* base = &lds[cur * TILEB];
    s16x8 kh[2], kl[2];
    kh[0] = *(const s16x8*)(base + koffs);
    kh[1] = *(const s16x8*)(base + 2048 + koffs);
    kl[0] = *(const s16x8*)(base + 4096 + koffs);
    kl[1] = *(const s16x8*)(base + 6144 + koffs);
    f32x4v s = {};
#pragma unroll
    for (int ks = 0; ks < 2; ++ks) {
      s = __builtin_amdgcn_mfma_f32_16x16x32_bf16(qfh[ks], kh[ks], s, 0, 0, 0);
      s = __builtin_amdgcn_mfma_f32_16x16x32_bf16(qfh[ks], kl[ks], s, 0, 0, 0);
      s = __builtin_amdgcn_mfma_f32_16x16x32_bf16(qfl[ks], kh[ks], s, 0, 0, 0);
    }
    int jg = (kt << 5) + pcol;
    int ig = m0 + prow;
#pragma unroll
    for (int r = 0; r < 4; ++r) {
      float p = (jg <= ig + r) ? __expf(s[r]) : 0.f;
      ps[r] += p;
      *(unsigned short*)(Pt + swz_off(prow + r, pcol * 2)) = f2bf(p);
    }
    __builtin_amdgcn_sched_barrier(0);
    asm volatile("s_waitcnt lgkmcnt(0)" ::: "memory");
    __builtin_amdgcn_s_barrier();
    __builtin_amdgcn_sched_barrier(0);
    s16x8 pa[2], vf[4];
#pragma unroll
    for (int mf = 0; mf < 2; ++mf) pa[mf] = *(const s16x8*)(Pt + paoff[mf]);
    const char* vbase = base + 8192;
#pragma unroll
    for (int nf = 0; nf < 4; ++nf) vf[nf] = *(const s16x8*)(vbase + voff[nf]);
    __builtin_amdgcn_s_setprio(1);
#pragma unroll
    for (int mf = 0; mf < 2; ++mf)
#pragma unroll
      for (int nf = 0; nf < 4; ++nf)
        accp[mf][nf] =
            __builtin_amdgcn_mfma_f32_16x16x32_bf16(pa[mf], vf[nf], accp[mf][nf], 0, 0, 0);
    __builtin_amdgcn_s_setprio(0);
    cur = (cur == 2) ? 0 : cur + 1;
    nxt = (nxt == 2) ? 0 : nxt + 1;
  }

#pragma unroll
  for (int r = 0; r < 4; ++r) {
    float v = ps[r];
    for (int msk = 1; msk < 16; msk <<= 1) v += __shfl_xor(v, msk, 64);
    if ((lane & 15) == 0) atomicAdd(&rs[prow + r], v);
  }
  __syncthreads();

  unsigned short* Cp = ctx + (size_t)(z * S_ + m0) * DKV_ + d0;
#pragma unroll
  for (int mf = 0; mf < 2; ++mf) {
    int lr0 = wr * 32 + mf * 16 + ((lane >> 4) << 2);
#pragma unroll
    for (int nf = 0; nf < 4; ++nf) {
      int lc = wc * 64 + nf * 16 + (lane & 15);
#pragma unroll
      for (int r = 0; r < 4; ++r) {
        float sc = 1.f / rs[lr0 + r];
        Cp[(size_t)(lr0 + r) * DKV_ + lc] = f2bf(accp[mf][nf][r] * sc);
      }
    }
  }
}

// ---------------- pipelined bf16 MFMA GEMM (wave 64x64) ----------------
template <int BM, int BN, bool TRANS_OUT, bool OUT_BF16>
__global__ __launch_bounds__(512, 4) void k_gemm256(
    const unsigned short* __restrict__ A, int lda,
    const unsigned short* __restrict__ BT, int ldbt,
    void* __restrict__ C, int ldc, int K) {
  constexpr int ABYTES = BM * 64;
  constexpr int BBYTES = BN * 64;
  constexpr int TILEB = ABYTES + BBYTES;
  constexpr int WARPS_M = 4;
  constexpr int WARPS_N = 2;
  constexpr int WM = BM / WARPS_M;
  constexpr int WN = BN / WARPS_N;
  constexpr int MF = WM / 16;
  constexpr int NF = WN / 16;
  constexpr int LPS = BM / 128 + BN / 128;
  __shared__ __attribute__((aligned(16))) char lds[3 * TILEB];

  int t = threadIdx.x;
  int gx = gridDim.x;
  int id = blockIdx.y * gx + blockIdx.x;
  int cpx = gx >> 3;
  int xcd = id & 7, rr = id >> 3;
  int bx = xcd * cpx + rr % cpx;
  int by = rr / cpx;
  int m0 = bx * BM, n0 = by * BN;

  const unsigned short* Ab = A + (size_t)m0 * lda;
  const unsigned short* Bb = BT + (size_t)n0 * ldbt;

  int lane = t & 63, wave = t >> 6;
  int wr = wave / WARPS_N, wc = wave % WARPS_N;
  int kb = (lane >> 4) << 4;
  int aoff[MF], boff[NF];
#pragma unroll
  for (int mf = 0; mf < MF; ++mf)
    aoff[mf] = swz_off(wr * WM + mf * 16 + (lane & 15), kb);
#pragma unroll
  for (int nf = 0; nf < NF; ++nf)
    boff[nf] = swz_off(wc * WN + nf * 16 + (lane & 15), kb);

  int NT = K >> 5;

  auto stage = [&](int kt, int buf) {
    int k0 = kt << 5;
    char* la = &lds[buf * TILEB];
    char* lb = la + ABYTES;
#pragma unroll
    for (int c = 0; c < BM / 128; ++c) {
      int q = c * 512 + t;
      int L = q >> 3;
      int slot = (q & 7) ^ (L & 7);
      int m = (L << 1) | (slot >> 2);
      int ke = (slot & 3) << 3;
      gl_lds16(Ab + (size_t)m * lda + k0 + ke, la + q * 16);
    }
#pragma unroll
    for (int c = 0; c < BN / 128; ++c) {
      int q = c * 512 + t;
      int L = q >> 3;
      int slot = (q & 7) ^ (L & 7);
      int n = (L << 1) | (slot >> 2);
      int ke = (slot & 3) << 3;
      gl_lds16(Bb + (size_t)n * ldbt + k0 + ke, lb + q * 16);
    }
  };

  f32x4v acc[MF][NF] = {};
  stage(0, 0);
  if (NT > 1) stage(1, 1);
  int cur = 0, nxt = 2;
  for (int kt = 0; kt < NT; ++kt) {
    __builtin_amdgcn_sched_barrier(0);
    if (kt + 1 < NT) {
      if constexpr (LPS == 2) asm volatile("s_waitcnt vmcnt(2)" ::: "memory");
      else asm volatile("s_waitcnt vmcnt(3)" ::: "memory");
    } else {
      asm volatile("s_waitcnt vmcnt(0)" ::: "memory");
    }
    __builtin_amdgcn_s_barrier();
    __builtin_amdgcn_sched_barrier(0);
    if (kt + 2 < NT) stage(kt + 2, nxt);
    const char* la = &lds[cur * TILEB];
    const char* lb = la + ABYTES;
    s16x8 af[MF], bf[NF];
#pragma unroll
    for (int mf = 0; mf < MF; ++mf) af[mf] = *(const s16x8*)(la + aoff[mf]);
#pragma unroll
    for (int nf = 0; nf < NF; ++nf) bf[nf] = *(const s16x8*)(lb + boff[nf]);
    __builtin_amdgcn_s_setprio(1);
#pragma unroll
    for (int mf = 0; mf < MF; ++mf)
#pragma unroll
      for (int nf = 0; nf < NF; ++nf)
        acc[mf][nf] =
            __builtin_amdgcn_mfma_f32_16x16x32_bf16(af[mf], bf[nf], acc[mf][nf], 0, 0, 0);
    __builtin_amdgcn_s_setprio(0);
    cur = (cur == 2) ? 0 : cur + 1;
    nxt = (nxt == 2) ? 0 : nxt + 1;
  }

#pragma unroll
  for (int mf = 0; mf < MF; ++mf) {
    int lrow = wr * WM + mf * 16 + ((lane >> 4) << 2);
#pragma unroll
    for (int nf = 0; nf < NF; ++nf) {
      int lcol = wc * WN + nf * 16 + (lane & 15);
      f32x4v v = acc[mf][nf];
      if (TRANS_OUT) {
        ushort4 o;
        o.x = f2bf(v[0]); o.y = f2bf(v[1]); o.z = f2bf(v[2]); o.w = f2bf(v[3]);
        unsigned short* Cp = (unsigned short*)C;
        *(ushort4*)&Cp[(size_t)(n0 + lcol) * ldc + m0 + lrow] = o;
      } else {
#pragma unroll
        for (int r = 0; r < 4; ++r) {
          if (OUT_BF16) {
            unsigned short* Cp = (unsigned short*)C;
            Cp[(size_t)(m0 + lrow + r) * ldc + n0 + lcol] = f2bf(v[r]);
          } else {
            float* Cp = (float*)C;
            Cp[(size_t)(m0 + lrow + r) * ldc + n0 + lcol] = v[r];
          }
        }
      }
    }
  }
}

extern "C" void kernel_launch(void* const* d_in, const int* in_sizes, int n_in,
                              void* d_out, int out_size, void* d_ws, size_t ws_size,
                              hipStream_t stream) {
  const float* hs = (const float*)d_in[0];
  const float* Wq = (const float*)d_in[2];
  const float* Wk = (const float*)d_in[3];
  const float* Wv = (const float*)d_in[4];
  const float* Wo = (const float*)d_in[5];
  float* out = (float*)d_out;

  char* w = (char*)d_ws;
  unsigned short* hsb = (unsigned short*)w; w += (size_t)B_ * S_ * H_ * 2;
  unsigned short* WvT = (unsigned short*)w; w += (size_t)DKV_ * H_ * 2;
  unsigned short* WoT = (unsigned short*)w; w += (size_t)H_ * DKV_ * 2;
  unsigned short* WqkTh = (unsigned short*)w; w += (size_t)128 * H_ * 2;
  unsigned short* WqkTl = (unsigned short*)w; w += (size_t)128 * H_ * 2;
  unsigned short* VT  = (unsigned short*)w; w += (size_t)DKV_ * B_ * S_ * 2;
  unsigned short* ctx = (unsigned short*)w; w += (size_t)B_ * S_ * DKV_ * 2;
  unsigned short* qkh = (unsigned short*)w; w += (size_t)B_ * S_ * 128 * 2;
  unsigned short* qkl = (unsigned short*)w; w += (size_t)B_ * S_ * 128 * 2;
  float* part = (float*)w; w += (size_t)4 * B_ * S_ * 128 * 4;

  // 1) WvT = Wv^T bf16
  k_transpose_bf16<<<dim3(DKV_ / 32, H_ / 32), 256, 0, stream>>>(Wv, WvT, H_, DKV_);
  // 2) WoT_eff
  k_build_wot<<<dim3(H_ / 32, DKV_ / 32), 256, 0, stream>>>(Wo, WoT);
  // 3) WqkT hi/lo
  k_build_wqkt<<<dim3(H_ / 32, 4), 256, 0, stream>>>(Wq, Wk, WqkTh, WqkTl);
  // 4) split-K q/k projection (fused fp32 conversion; writes hsb) -> partials
  k_qk_split<<<dim3(B_ * S_ / 32, 4), 512, 0, stream>>>(hs, WqkTh, WqkTl, hsb, part);
  // 5) reduce partials -> qkh/qkl
  k_qk_reduce<<<(B_ * S_ * 128) / (256 * 4), 256, 0, stream>>>(part, qkh, qkl);
  // 6) V projection (transposed epilogue -> VT): BM=256xBN=128, wave 64x64
  k_gemm256<256, 128, true, true>
      <<<dim3(B_ * S_ / 256, DKV_ / 128), 512, 0, stream>>>(
      hsb, H_, WvT, H_, VT, B_ * S_, H_);
  // 7) fused scores+exp+rowsum+PV -> ctx (512 blocks, 2/CU, paired causal)
  k_attn_fused<<<dim3(32, 4, B_), 512, 0, stream>>>(qkh, qkl, VT, ctx);
  // 8) out = ctx @ WoT^T (fp32 out): BM=256xBN=128, wave 64x64
  k_gemm256<256, 128, false, false>
      <<<dim3(B_ * S_ / 256, H_ / 128), 512, 0, stream>>>(
      ctx, DKV_, WoT, DKV_, out, H_, DKV_);
}